// Round 17
// baseline (215.791 us; speedup 1.0000x reference)
//
#include <hip/hip_runtime.h>
#include <stdint.h>
#include <type_traits>

typedef __attribute__((ext_vector_type(8))) short bf16x8;
typedef __attribute__((ext_vector_type(4))) float f32x4;
typedef __attribute__((ext_vector_type(16))) float f32x16;

#define BB 4
#define NH 16
#define TT 2048
#define HD 64
#define CC 1024

__device__ __forceinline__ unsigned short f2bf(float f) {
  unsigned int u = __builtin_bit_cast(unsigned int, f);
  u += 0x7fff + ((u >> 16) & 1);
  return (unsigned short)(u >> 16);
}

__device__ __forceinline__ float fast_exp2(float x) {
#if __has_builtin(__builtin_amdgcn_exp2f)
  return __builtin_amdgcn_exp2f(x);
#else
  return exp2f(x);
#endif
}

__device__ __forceinline__ unsigned int cvtpk(float lo, float hi) {
  unsigned int r;
  asm("v_cvt_pk_bf16_f32 %0, %1, %2" : "=v"(r) : "v"(lo), "v"(hi));
  return r;
}

__device__ __forceinline__ void plswap(unsigned int& a, unsigned int& b) {
#if __has_builtin(__builtin_amdgcn_permlane32_swap)
  auto r = __builtin_amdgcn_permlane32_swap(a, b, false, false);
  a = r[0];
  b = r[1];
#else
  unsigned int as = __shfl_xor((int)a, 32), bs = __shfl_xor((int)b, 32);
  bool hi = (threadIdx.x & 32) != 0;
  unsigned int na = hi ? bs : a;
  unsigned int nb = hi ? b : as;
  a = na; b = nb;
#endif
}

__device__ __forceinline__ float partner32(float x, bool hi) {
  unsigned int a = __builtin_bit_cast(unsigned int, x), b = a;
  plswap(a, b);
  return __builtin_bit_cast(float, hi ? a : b);
}

__device__ __forceinline__ void g2l16(const void* g, void* s) {
  __builtin_amdgcn_global_load_lds(
      (const __attribute__((address_space(1))) unsigned int*)g,
      (__attribute__((address_space(3))) unsigned int*)s, 16, 0, 0);
}

// ---------------- fused prep: casts + weight transposes + mask -------------
// blocks [0,16384): cast x/ft f32->bf16 (1024 elems/block)
// blocks [16384,20480): weight transpose+cast, 32x32 tiles, 4 weights
// blocks [20480,20512): mask int -> float 0/1
__global__ __launch_bounds__(256) void prep_fused(
    const float* __restrict__ x, const float* __restrict__ ft,
    const float* __restrict__ wq, const float* __restrict__ wk,
    const float* __restrict__ wv, const float* __restrict__ wo,
    const int* __restrict__ mask,
    unsigned short* __restrict__ xb, unsigned short* __restrict__ fb,
    unsigned short* __restrict__ wqkvt, unsigned short* __restrict__ wot,
    float* __restrict__ m01) {
  __shared__ float tile[32][33];
  const int bid = blockIdx.x, t = threadIdx.x;
  if (bid < 16384) {
    const float* in = (bid >> 13) ? ft : x;
    unsigned short* out = (bid >> 13) ? fb : xb;
    int i = ((bid & 8191) * 256 + t) * 4;
    float4 v = *(const float4*)(in + i);
    ushort4 o;
    o.x = f2bf(v.x); o.y = f2bf(v.y); o.z = f2bf(v.z); o.w = f2bf(v.w);
    *(ushort4*)(out + i) = o;
  } else if (bid < 20480) {
    const int bid2 = bid - 16384;
    const int z = bid2 >> 10, rem = bid2 & 1023;
    const float* w = (z == 0) ? wq : (z == 1) ? wk : (z == 2) ? wv : wo;
    unsigned short* wt = (z < 3) ? wqkvt + (size_t)z * CC * CC : wot;
    const int nb = (rem & 31) * 32, kb = (rem >> 5) * 32;
    const int tx = t & 31, ty = t >> 5;
#pragma unroll
    for (int r = ty; r < 32; r += 8)
      tile[r][tx] = w[(size_t)(kb + r) * CC + nb + tx];
    __syncthreads();
#pragma unroll
    for (int r = ty; r < 32; r += 8)
      wt[(size_t)(nb + r) * CC + kb + tx] = f2bf(tile[tx][r]);
  } else {
    int i = (bid - 20480) * 256 + t;
    m01[i] = mask[i] ? 1.0f : 0.0f;
  }
}

// ---------------- fused QKV GEMM: r12 form (BK=32, 16KB, chunk swizzle) ----
__global__ __launch_bounds__(256) void gemm_qkv(
    const unsigned short* __restrict__ xb, const unsigned short* __restrict__ fb,
    const unsigned short* __restrict__ Wt,
    const float* __restrict__ bq, const float* __restrict__ bk,
    const float* __restrict__ bv, const float* __restrict__ m01,
    unsigned short* __restrict__ Qb, unsigned short* __restrict__ Kb,
    unsigned short* __restrict__ Vtb, float qscale) {
  __shared__ unsigned short As[128 * 32];
  __shared__ unsigned short Bs[128 * 32];
  int lin = blockIdx.y * gridDim.x + blockIdx.x;
  int cpx = (gridDim.x * gridDim.y) >> 3;
  int sw = (lin & 7) * cpx + (lin >> 3);
  const int n0g = (sw % 24) * 128;
  const int m0 = (sw / 24) * 128;
  const int sec = n0g >> 10;
  const int n0 = n0g & (CC - 1);
  const unsigned short* A = (sec == 0) ? xb : fb;
  const unsigned short* Bt = Wt + (size_t)n0g * CC;

  const int t = threadIdx.x, l = t & 63, w = t >> 6;
  const int lr = l & 15, lg = l >> 4;
  const int wr = w >> 1, wc = w & 1;

  const int c1 = t + 256;
  const int r0 = t >> 2, k0e = (((t & 3) ^ (r0 & 3)) * 8);
  const int r1 = c1 >> 2, k1e = (((c1 & 3) ^ (r1 & 3)) * 8);
  const unsigned short* gA0 = A + (size_t)(m0 + r0) * CC + k0e;
  const unsigned short* gA1 = A + (size_t)(m0 + r1) * CC + k1e;
  const unsigned short* gB0 = Bt + (size_t)r0 * CC + k0e;
  const unsigned short* gB1 = Bt + (size_t)r1 * CC + k1e;
  auto stage = [&]() {
    g2l16(gA0, (char*)As + t * 16);
    g2l16(gA1, (char*)As + t * 16 + 4096);
    g2l16(gB0, (char*)Bs + t * 16);
    g2l16(gB1, (char*)Bs + t * 16 + 4096);
    gA0 += 32; gA1 += 32; gB0 += 32; gB1 += 32;
  };

  const int colx = (lg * 16) ^ ((lr & 3) << 4);
  const int abase = (wr * 64 + lr) * 64 + colx;
  const int bbase = (wc * 64 + lr) * 64 + colx;

  f32x4 acc[4][4] = {};
  for (int j = 0; j < 32; ++j) {
    stage();
    asm volatile("s_waitcnt vmcnt(0)" ::: "memory");
    __syncthreads();
    bf16x8 af[4], bfr[4];
#pragma unroll
    for (int mi = 0; mi < 4; ++mi)
      af[mi] = *(const bf16x8*)((const char*)As + abase + mi * 1024);
#pragma unroll
    for (int nj = 0; nj < 4; ++nj)
      bfr[nj] = *(const bf16x8*)((const char*)Bs + bbase + nj * 1024);
#pragma unroll
    for (int mi = 0; mi < 4; ++mi)
#pragma unroll
      for (int nj = 0; nj < 4; ++nj)
        acc[mi][nj] = __builtin_amdgcn_mfma_f32_16x16x32_bf16(
            af[mi], bfr[nj], acc[mi][nj], 0, 0, 0);
    __syncthreads();
  }

  if (sec < 2) {
    const float* bp = (sec == 0) ? bq : bk;
    const float scale = (sec == 0) ? qscale : 1.0f;
    unsigned short* dst = (sec == 0) ? Qb : Kb;
#pragma unroll
    for (int mi = 0; mi < 4; ++mi) {
#pragma unroll
      for (int nj = 0; nj < 4; ++nj) {
        int col = n0 + wc * 64 + nj * 16 + lr;
        float bias = bp[col];
#pragma unroll
        for (int j = 0; j < 4; ++j) {
          int rowm = m0 + wr * 64 + mi * 16 + lg * 4 + j;
          float v = (acc[mi][nj][j] + bias) * scale;
          int b_ = rowm >> 11, tq = rowm & (TT - 1);
          int h_ = col >> 6, d_ = col & (HD - 1);
          dst[((size_t)((b_ * NH + h_) * TT + tq) << 6) + d_] = f2bf(v);
        }
      }
    }
  } else {
#pragma unroll
    for (int mi = 0; mi < 4; ++mi) {
      int rowb = m0 + wr * 64 + mi * 16 + lg * 4;
      int b_ = rowb >> 11, tq = rowb & (TT - 1);
      f32x4 mv = *(const f32x4*)(m01 + rowb);
#pragma unroll
      for (int nj = 0; nj < 4; ++nj) {
        int col = n0 + wc * 64 + nj * 16 + lr;
        float bias = bv[col];
        int h_ = col >> 6, d_ = col & (HD - 1);
        unsigned short pk[4];
#pragma unroll
        for (int j = 0; j < 4; ++j)
          pk[j] = f2bf((acc[mi][nj][j] + bias) * mv[j]);
        *(ushort4*)(Vtb + ((size_t)((b_ * NH + h_) * HD + d_) << 11) + tq) =
            *(ushort4*)pk;
      }
    }
  }
}

// ---------------- O-projection GEMM: BK=64, swizzled LDS (r11 form) --------
__global__ __launch_bounds__(256) void gemm_out(
    const unsigned short* __restrict__ A, const unsigned short* __restrict__ Bt,
    const float* __restrict__ bias, float* __restrict__ Out) {
  __shared__ unsigned short As[128 * 64];
  __shared__ unsigned short Bs[128 * 64];
  int lin = blockIdx.y * gridDim.x + blockIdx.x;
  int cpx = (gridDim.x * gridDim.y) >> 3;
  int sw = (lin & 7) * cpx + (lin >> 3);
  const int n0 = (sw % 8) * 128;
  const int m0 = (sw / 8) * 128;
  const int t = threadIdx.x, l = t & 63, w = t >> 6;
  const int lr = l & 15, lg = l >> 4;
  const int wr = w >> 1, wc = w & 1;

  const int sR = t >> 3;
  const int sx = ((t & 7) * 16) ^ ((sR & 7) << 4);
  const unsigned short* gA = A + (size_t)(m0 + sR) * CC + (sx >> 1);
  const unsigned short* gB = Bt + (size_t)(n0 + sR) * CC + (sx >> 1);
  auto stage = [&]() {
#pragma unroll
    for (int i = 0; i < 4; ++i) {
      g2l16(gA + (size_t)(i * 32) * CC, (char*)As + t * 16 + i * 4096);
      g2l16(gB + (size_t)(i * 32) * CC, (char*)Bs + t * 16 + i * 4096);
    }
    gA += 64; gB += 64;
  };

  const int axs = (lr & 7) << 4;
  const int col0 = (lg * 16) ^ axs;
  const int col1 = (64 + lg * 16) ^ axs;
  const int abase = (wr * 64 + lr) * 128;
  const int bbase = (wc * 64 + lr) * 128;

  f32x4 acc[4][4] = {};
  for (int j = 0; j < 16; ++j) {
    stage();
    asm volatile("s_waitcnt vmcnt(0)" ::: "memory");
    __syncthreads();
    bf16x8 af[4], bfr[4];
#pragma unroll
    for (int mi = 0; mi < 4; ++mi)
      af[mi] = *(const bf16x8*)((const char*)As + abase + mi * 2048 + col0);
#pragma unroll
    for (int nj = 0; nj < 4; ++nj)
      bfr[nj] = *(const bf16x8*)((const char*)Bs + bbase + nj * 2048 + col0);
#pragma unroll
    for (int mi = 0; mi < 4; ++mi)
#pragma unroll
      for (int nj = 0; nj < 4; ++nj)
        acc[mi][nj] = __builtin_amdgcn_mfma_f32_16x16x32_bf16(
            af[mi], bfr[nj], acc[mi][nj], 0, 0, 0);
#pragma unroll
    for (int mi = 0; mi < 4; ++mi)
      af[mi] = *(const bf16x8*)((const char*)As + abase + mi * 2048 + col1);
#pragma unroll
    for (int nj = 0; nj < 4; ++nj)
      bfr[nj] = *(const bf16x8*)((const char*)Bs + bbase + nj * 2048 + col1);
#pragma unroll
    for (int mi = 0; mi < 4; ++mi)
#pragma unroll
      for (int nj = 0; nj < 4; ++nj)
        acc[mi][nj] = __builtin_amdgcn_mfma_f32_16x16x32_bf16(
            af[mi], bfr[nj], acc[mi][nj], 0, 0, 0);
    __syncthreads();
  }

#pragma unroll
  for (int mi = 0; mi < 4; ++mi) {
#pragma unroll
    for (int nj = 0; nj < 4; ++nj) {
      int col = n0 + wc * 64 + nj * 16 + lr;
      float bv = bias[col];
#pragma unroll
      for (int j = 0; j < 4; ++j) {
        int rowm = m0 + wr * 64 + mi * 16 + lg * 4 + j;
        Out[(size_t)rowm * CC + col] = acc[mi][nj][j] + bv;
      }
    }
  }
}

// ---------------- flash attention v9 (known-good, unchanged) ---------------
__global__ __launch_bounds__(256) void attn_fwd9(
    const unsigned short* __restrict__ Q, const unsigned short* __restrict__ K,
    const unsigned short* __restrict__ Vt, const float* __restrict__ m01,
    unsigned short* __restrict__ O) {
  __shared__ __attribute__((aligned(64))) char ldsb[40960];
  const int t = threadIdx.x, l = t & 63, w = t >> 6;
  const int q5 = l & 31, hig = l >> 5;
  const bool hib = hig != 0;
  int lin = blockIdx.y * gridDim.x + blockIdx.x;
  int sw = (lin & 7) * 128 + (lin >> 3);
  const int bx = sw & 15, bh = sw >> 4;
  const int b_ = bh >> 4, h_ = bh & (NH - 1);
  const int q = bx * 128 + w * 32 + q5;
  const size_t base = (size_t)bh * TT * HD;
  const unsigned short* Kg = K + base;
  const unsigned short* Vg = Vt + (size_t)bh * HD * TT;

  bf16x8 qf[4];
  {
    const unsigned short* qp = Q + base + (size_t)q * HD + 8 * hig;
#pragma unroll
    for (int dk = 0; dk < 4; ++dk) qf[dk] = *(const bf16x8*)(qp + dk * 16);
  }

  int ka[4];
  {
    int swz = (q5 & 7) << 4;
#pragma unroll
    for (int dk = 0; dk < 4; ++dk)
      ka[dk] = q5 * 128 + ((dk * 32 + hig * 16) ^ swz);
  }
  int moff = 32768 + hig * 16;

  const int s1 = t + 256;
  const int r0 = t >> 3, c0 = (t & 7) * 16, x0 = c0 ^ ((r0 & 7) << 4);
  const int r1 = s1 >> 3, c1 = (s1 & 7) * 16, x1 = c1 ^ ((r1 & 7) << 4);
  const unsigned short* gk0 = Kg + r0 * HD + (x0 >> 1);
  const unsigned short* gk1 = Kg + r1 * HD + (x1 >> 1);
  const unsigned short* gv0 = Vg + (size_t)r0 * TT + (x0 >> 1);
  const unsigned short* gv1 = Vg + (size_t)r1 * TT + (x1 >> 1);

  auto stage = [&](int boff) {
    g2l16(gk0, ldsb + t * 16 + boff);
    g2l16(gk1, ldsb + t * 16 + 4096 + boff);
    g2l16(gv0, ldsb + 16384 + t * 16 + boff);
    g2l16(gv1, ldsb + 16384 + t * 16 + 4096 + boff);
    gk0 += 4096; gk1 += 4096; gv0 += 64; gv1 += 64;
  };

  f32x16 ot[2];
#pragma unroll
  for (int i = 0; i < 16; ++i) { ot[0][i] = 0.f; ot[1][i] = 0.f; }
  float l0 = 0.f, l1 = 0.f, l2 = 0.f, l3 = 0.f;

  {
    const float* mg = m01 + (size_t)b_ * TT;
#pragma unroll
    for (int i = 0; i < 2; ++i) {
      int s = t + i * 256;
      g2l16(mg + s * 4, ldsb + 32768 + s * 16);
    }
  }
  stage(0);
  asm volatile("s_waitcnt vmcnt(0)" ::: "memory");
  __syncthreads();

  auto compute = [&](auto Bc) {
    constexpr int BO = decltype(Bc)::value;
    constexpr int MO = BO ? 256 : 0;
#pragma unroll
    for (int kk = 0; kk < 2; ++kk) {
      f32x16 s = {};
      __builtin_amdgcn_s_setprio(1);
#pragma unroll
      for (int dk = 0; dk < 4; ++dk) {
        bf16x8 kf = *(const bf16x8*)(ldsb + ka[dk] + kk * 4096 + BO);
        s = __builtin_amdgcn_mfma_f32_32x32x16_bf16(kf, qf[dk], s, 0, 0, 0);
      }
      __builtin_amdgcn_s_setprio(0);

      unsigned int wl[4], wh[4];
#pragma unroll
      for (int g = 0; g < 4; ++g) {
        int i = g * 4;
        float e0 = fast_exp2(s[i + 0]);
        float e1 = fast_exp2(s[i + 1]);
        float e2 = fast_exp2(s[i + 2]);
        float e3 = fast_exp2(s[i + 3]);
        f32x4 mk = *(const f32x4*)(ldsb + moff + MO + kk * 128 + g * 32);
        l0 = fmaf(e0, mk[0], l0);
        l1 = fmaf(e1, mk[1], l1);
        l2 = fmaf(e2, mk[2], l2);
        l3 = fmaf(e3, mk[3], l3);
        wl[g] = cvtpk(e0, e1);
        wh[g] = cvtpk(e2, e3);
      }

      bf16x8 pa[2];
#pragma unroll
      for (int kh = 0; kh < 2; ++kh) {
        const int gA = 2 * kh, gB = gA + 1;
        unsigned int a0 = wl[gA], b0 = wl[gB];
        unsigned int a1 = wh[gA], b1 = wh[gB];
        plswap(a0, b0);
        plswap(a1, b1);
        unsigned int pw[4] = {a0, a1, b0, b1};
        pa[kh] = *(bf16x8*)pw;
      }

      __builtin_amdgcn_s_setprio(1);
#pragma unroll
      for (int kh = 0; kh < 2; ++kh) {
        const int ks = kk * 2 + kh;
        bf16x8 vf0 = *(const bf16x8*)(ldsb + ka[ks] + 16384 + BO);
        bf16x8 vf1 = *(const bf16x8*)(ldsb + ka[ks] + 16384 + 4096 + BO);
        ot[0] = __builtin_amdgcn_mfma_f32_32x32x16_bf16(vf0, pa[kh], ot[0], 0, 0, 0);
        ot[1] = __builtin_amdgcn_mfma_f32_32x32x16_bf16(vf1, pa[kh], ot[1], 0, 0, 0);
      }
      __builtin_amdgcn_s_setprio(0);
    }
  };

  for (int j = 0; j < 16; ++j) {
    stage(8192);
    compute(std::integral_constant<int, 0>{});
    asm volatile("s_waitcnt vmcnt(0)" ::: "memory");
    __syncthreads();
    if (j < 15) stage(0);
    compute(std::integral_constant<int, 8192>{});
    asm volatile("s_waitcnt vmcnt(0)" ::: "memory");
    __syncthreads();
    moff += 512;
  }

  float l_ = (l0 + l1) + (l2 + l3);
  float l_tot = l_ + partner32(l_, hib);
  const float inv = 1.f / l_tot;
  unsigned short* orow = O + ((size_t)(b_ * TT) + q) * CC + h_ * 64 + 4 * hig;
#pragma unroll
  for (int dt = 0; dt < 2; ++dt)
#pragma unroll
    for (int g = 0; g < 4; ++g) {
      unsigned short pk4[4];
#pragma unroll
      for (int j = 0; j < 4; ++j) pk4[j] = f2bf(ot[dt][4 * g + j] * inv);
      *(ushort4*)(orow + dt * 32 + 8 * g) = *(ushort4*)pk4;
    }
}

extern "C" void kernel_launch(void* const* d_in, const int* in_sizes, int n_in,
                              void* d_out, int out_size, void* d_ws, size_t ws_size,
                              hipStream_t stream) {
  const float* x  = (const float*)d_in[0];
  const float* ft = (const float*)d_in[1];
  const int* mask = (const int*)d_in[2];
  const float* wq = (const float*)d_in[3];
  const float* bq = (const float*)d_in[4];
  const float* wk = (const float*)d_in[5];
  const float* bk = (const float*)d_in[6];
  const float* wv = (const float*)d_in[7];
  const float* bv = (const float*)d_in[8];
  const float* wo = (const float*)d_in[9];
  const float* bo = (const float*)d_in[10];
  float* out = (float*)d_out;

  char* ws = (char*)d_ws;
  const size_t NTOK = (size_t)BB * TT;   // 8192
  const size_t SB = NTOK * CC * 2;       // 16 MiB
  unsigned short* xb   = (unsigned short*)ws; ws += SB;
  unsigned short* fb   = (unsigned short*)ws; ws += SB;
  unsigned short* Qb   = (unsigned short*)ws; ws += SB;
  unsigned short* Kb   = (unsigned short*)ws; ws += SB;
  unsigned short* Vtb  = (unsigned short*)ws; ws += SB;   // V^T (b,h,d,t)
  unsigned short* AO   = (unsigned short*)ws; ws += SB;
  unsigned short* wqkvt = (unsigned short*)ws; ws += (size_t)3 * CC * CC * 2;
  unsigned short* wot   = (unsigned short*)ws; ws += (size_t)CC * CC * 2;
  float* m01 = (float*)ws; ws += NTOK * 4;

  prep_fused<<<20512, 256, 0, stream>>>(x, ft, wq, wk, wv, wo, mask,
                                        xb, fb, wqkvt, wot, m01);

  const float qscale = 0.125f * 1.44269504f;  // 1/sqrt(64) * log2(e)
  dim3 gq(24, 64);  // 1536 blocks
  gemm_qkv<<<gq, 256, 0, stream>>>(xb, fb, wqkvt, bq, bk, bv, m01,
                                   Qb, Kb, Vtb, qscale);

  dim3 ga(16, 64);  // 1024 blocks
  attn_fwd9<<<ga, 256, 0, stream>>>(Qb, Kb, Vtb, m01, AO);

  dim3 go(8, 64);   // 512 blocks
  gemm_out<<<go, 256, 0, stream>>>(AO, wot, bo, out);
}

// Round 18
// 212.084 us; speedup vs baseline: 1.0175x; 1.0175x over previous
//
#include <hip/hip_runtime.h>
#include <stdint.h>
#include <type_traits>

typedef __attribute__((ext_vector_type(8))) short bf16x8;
typedef __attribute__((ext_vector_type(4))) float f32x4;
typedef __attribute__((ext_vector_type(16))) float f32x16;

#define BB 4
#define NH 16
#define TT 2048
#define HD 64
#define CC 1024

__device__ __forceinline__ unsigned short f2bf(float f) {
  unsigned int u = __builtin_bit_cast(unsigned int, f);
  u += 0x7fff + ((u >> 16) & 1);
  return (unsigned short)(u >> 16);
}

__device__ __forceinline__ float fast_exp2(float x) {
#if __has_builtin(__builtin_amdgcn_exp2f)
  return __builtin_amdgcn_exp2f(x);
#else
  return exp2f(x);
#endif
}

__device__ __forceinline__ unsigned int cvtpk(float lo, float hi) {
  unsigned int r;
  asm("v_cvt_pk_bf16_f32 %0, %1, %2" : "=v"(r) : "v"(lo), "v"(hi));
  return r;
}

__device__ __forceinline__ void plswap(unsigned int& a, unsigned int& b) {
#if __has_builtin(__builtin_amdgcn_permlane32_swap)
  auto r = __builtin_amdgcn_permlane32_swap(a, b, false, false);
  a = r[0];
  b = r[1];
#else
  unsigned int as = __shfl_xor((int)a, 32), bs = __shfl_xor((int)b, 32);
  bool hi = (threadIdx.x & 32) != 0;
  unsigned int na = hi ? bs : a;
  unsigned int nb = hi ? b : as;
  a = na; b = nb;
#endif
}

__device__ __forceinline__ float partner32(float x, bool hi) {
  unsigned int a = __builtin_bit_cast(unsigned int, x), b = a;
  plswap(a, b);
  return __builtin_bit_cast(float, hi ? a : b);
}

__device__ __forceinline__ void g2l16(const void* g, void* s) {
  __builtin_amdgcn_global_load_lds(
      (const __attribute__((address_space(1))) unsigned int*)g,
      (__attribute__((address_space(3))) unsigned int*)s, 16, 0, 0);
}

// ---------------- fused prep: casts + weight transposes + mask -------------
// blocks [0,16384): cast x/ft f32->bf16 (1024 elems/block)
// blocks [16384,20480): weight transpose+cast, 32x32 tiles, 4 weights
// blocks [20480,20512): mask int -> float 0/1
__global__ __launch_bounds__(256) void prep_fused(
    const float* __restrict__ x, const float* __restrict__ ft,
    const float* __restrict__ wq, const float* __restrict__ wk,
    const float* __restrict__ wv, const float* __restrict__ wo,
    const int* __restrict__ mask,
    unsigned short* __restrict__ xb, unsigned short* __restrict__ fb,
    unsigned short* __restrict__ wqkvt, unsigned short* __restrict__ wot,
    float* __restrict__ m01) {
  __shared__ float tile[32][33];
  const int bid = blockIdx.x, t = threadIdx.x;
  if (bid < 16384) {
    const float* in = (bid >> 13) ? ft : x;
    unsigned short* out = (bid >> 13) ? fb : xb;
    int i = ((bid & 8191) * 256 + t) * 4;
    float4 v = *(const float4*)(in + i);
    ushort4 o;
    o.x = f2bf(v.x); o.y = f2bf(v.y); o.z = f2bf(v.z); o.w = f2bf(v.w);
    *(ushort4*)(out + i) = o;
  } else if (bid < 20480) {
    const int bid2 = bid - 16384;
    const int z = bid2 >> 10, rem = bid2 & 1023;
    const float* w = (z == 0) ? wq : (z == 1) ? wk : (z == 2) ? wv : wo;
    unsigned short* wt = (z < 3) ? wqkvt + (size_t)z * CC * CC : wot;
    const int nb = (rem & 31) * 32, kb = (rem >> 5) * 32;
    const int tx = t & 31, ty = t >> 5;
#pragma unroll
    for (int r = ty; r < 32; r += 8)
      tile[r][tx] = w[(size_t)(kb + r) * CC + nb + tx];
    __syncthreads();
#pragma unroll
    for (int r = ty; r < 32; r += 8)
      wt[(size_t)(nb + r) * CC + kb + tx] = f2bf(tile[tx][r]);
  } else {
    int i = (bid - 20480) * 256 + t;
    m01[i] = mask[i] ? 1.0f : 0.0f;
  }
}

// ---------------- fused QKV GEMM: r12 form (BK=32, 16KB, chunk swizzle) ----
__global__ __launch_bounds__(256) void gemm_qkv(
    const unsigned short* __restrict__ xb, const unsigned short* __restrict__ fb,
    const unsigned short* __restrict__ Wt,
    const float* __restrict__ bq, const float* __restrict__ bk,
    const float* __restrict__ bv, const float* __restrict__ m01,
    unsigned short* __restrict__ Qb, unsigned short* __restrict__ Kb,
    unsigned short* __restrict__ Vtb, float qscale) {
  __shared__ unsigned short As[128 * 32];
  __shared__ unsigned short Bs[128 * 32];
  int lin = blockIdx.y * gridDim.x + blockIdx.x;
  int cpx = (gridDim.x * gridDim.y) >> 3;
  int sw = (lin & 7) * cpx + (lin >> 3);
  const int n0g = (sw % 24) * 128;
  const int m0 = (sw / 24) * 128;
  const int sec = n0g >> 10;
  const int n0 = n0g & (CC - 1);
  const unsigned short* A = (sec == 0) ? xb : fb;
  const unsigned short* Bt = Wt + (size_t)n0g * CC;

  const int t = threadIdx.x, l = t & 63, w = t >> 6;
  const int lr = l & 15, lg = l >> 4;
  const int wr = w >> 1, wc = w & 1;

  const int c1 = t + 256;
  const int r0 = t >> 2, k0e = (((t & 3) ^ (r0 & 3)) * 8);
  const int r1 = c1 >> 2, k1e = (((c1 & 3) ^ (r1 & 3)) * 8);
  const unsigned short* gA0 = A + (size_t)(m0 + r0) * CC + k0e;
  const unsigned short* gA1 = A + (size_t)(m0 + r1) * CC + k1e;
  const unsigned short* gB0 = Bt + (size_t)r0 * CC + k0e;
  const unsigned short* gB1 = Bt + (size_t)r1 * CC + k1e;
  auto stage = [&]() {
    g2l16(gA0, (char*)As + t * 16);
    g2l16(gA1, (char*)As + t * 16 + 4096);
    g2l16(gB0, (char*)Bs + t * 16);
    g2l16(gB1, (char*)Bs + t * 16 + 4096);
    gA0 += 32; gA1 += 32; gB0 += 32; gB1 += 32;
  };

  const int colx = (lg * 16) ^ ((lr & 3) << 4);
  const int abase = (wr * 64 + lr) * 64 + colx;
  const int bbase = (wc * 64 + lr) * 64 + colx;

  f32x4 acc[4][4] = {};
  for (int j = 0; j < 32; ++j) {
    stage();
    asm volatile("s_waitcnt vmcnt(0)" ::: "memory");
    __syncthreads();
    bf16x8 af[4], bfr[4];
#pragma unroll
    for (int mi = 0; mi < 4; ++mi)
      af[mi] = *(const bf16x8*)((const char*)As + abase + mi * 1024);
#pragma unroll
    for (int nj = 0; nj < 4; ++nj)
      bfr[nj] = *(const bf16x8*)((const char*)Bs + bbase + nj * 1024);
#pragma unroll
    for (int mi = 0; mi < 4; ++mi)
#pragma unroll
      for (int nj = 0; nj < 4; ++nj)
        acc[mi][nj] = __builtin_amdgcn_mfma_f32_16x16x32_bf16(
            af[mi], bfr[nj], acc[mi][nj], 0, 0, 0);
    __syncthreads();
  }

  if (sec < 2) {
    const float* bp = (sec == 0) ? bq : bk;
    const float scale = (sec == 0) ? qscale : 1.0f;
    unsigned short* dst = (sec == 0) ? Qb : Kb;
#pragma unroll
    for (int mi = 0; mi < 4; ++mi) {
#pragma unroll
      for (int nj = 0; nj < 4; ++nj) {
        int col = n0 + wc * 64 + nj * 16 + lr;
        float bias = bp[col];
#pragma unroll
        for (int j = 0; j < 4; ++j) {
          int rowm = m0 + wr * 64 + mi * 16 + lg * 4 + j;
          float v = (acc[mi][nj][j] + bias) * scale;
          int b_ = rowm >> 11, tq = rowm & (TT - 1);
          int h_ = col >> 6, d_ = col & (HD - 1);
          dst[((size_t)((b_ * NH + h_) * TT + tq) << 6) + d_] = f2bf(v);
        }
      }
    }
  } else {
#pragma unroll
    for (int mi = 0; mi < 4; ++mi) {
      int rowb = m0 + wr * 64 + mi * 16 + lg * 4;
      int b_ = rowb >> 11, tq = rowb & (TT - 1);
      f32x4 mv = *(const f32x4*)(m01 + rowb);
#pragma unroll
      for (int nj = 0; nj < 4; ++nj) {
        int col = n0 + wc * 64 + nj * 16 + lr;
        float bias = bv[col];
        int h_ = col >> 6, d_ = col & (HD - 1);
        unsigned short pk[4];
#pragma unroll
        for (int j = 0; j < 4; ++j)
          pk[j] = f2bf((acc[mi][nj][j] + bias) * mv[j]);
        *(ushort4*)(Vtb + ((size_t)((b_ * NH + h_) * HD + d_) << 11) + tq) =
            *(ushort4*)pk;
      }
    }
  }
}

// ---------------- O-projection GEMM: BK=64, swizzled LDS (r11 form) --------
__global__ __launch_bounds__(256) void gemm_out(
    const unsigned short* __restrict__ A, const unsigned short* __restrict__ Bt,
    const float* __restrict__ bias, float* __restrict__ Out) {
  __shared__ unsigned short As[128 * 64];
  __shared__ unsigned short Bs[128 * 64];
  int lin = blockIdx.y * gridDim.x + blockIdx.x;
  int cpx = (gridDim.x * gridDim.y) >> 3;
  int sw = (lin & 7) * cpx + (lin >> 3);
  const int n0 = (sw % 8) * 128;
  const int m0 = (sw / 8) * 128;
  const int t = threadIdx.x, l = t & 63, w = t >> 6;
  const int lr = l & 15, lg = l >> 4;
  const int wr = w >> 1, wc = w & 1;

  const int sR = t >> 3;
  const int sx = ((t & 7) * 16) ^ ((sR & 7) << 4);
  const unsigned short* gA = A + (size_t)(m0 + sR) * CC + (sx >> 1);
  const unsigned short* gB = Bt + (size_t)(n0 + sR) * CC + (sx >> 1);
  auto stage = [&]() {
#pragma unroll
    for (int i = 0; i < 4; ++i) {
      g2l16(gA + (size_t)(i * 32) * CC, (char*)As + t * 16 + i * 4096);
      g2l16(gB + (size_t)(i * 32) * CC, (char*)Bs + t * 16 + i * 4096);
    }
    gA += 64; gB += 64;
  };

  const int axs = (lr & 7) << 4;
  const int col0 = (lg * 16) ^ axs;
  const int col1 = (64 + lg * 16) ^ axs;
  const int abase = (wr * 64 + lr) * 128;
  const int bbase = (wc * 64 + lr) * 128;

  f32x4 acc[4][4] = {};
  for (int j = 0; j < 16; ++j) {
    stage();
    asm volatile("s_waitcnt vmcnt(0)" ::: "memory");
    __syncthreads();
    bf16x8 af[4], bfr[4];
#pragma unroll
    for (int mi = 0; mi < 4; ++mi)
      af[mi] = *(const bf16x8*)((const char*)As + abase + mi * 2048 + col0);
#pragma unroll
    for (int nj = 0; nj < 4; ++nj)
      bfr[nj] = *(const bf16x8*)((const char*)Bs + bbase + nj * 2048 + col0);
#pragma unroll
    for (int mi = 0; mi < 4; ++mi)
#pragma unroll
      for (int nj = 0; nj < 4; ++nj)
        acc[mi][nj] = __builtin_amdgcn_mfma_f32_16x16x32_bf16(
            af[mi], bfr[nj], acc[mi][nj], 0, 0, 0);
#pragma unroll
    for (int mi = 0; mi < 4; ++mi)
      af[mi] = *(const bf16x8*)((const char*)As + abase + mi * 2048 + col1);
#pragma unroll
    for (int nj = 0; nj < 4; ++nj)
      bfr[nj] = *(const bf16x8*)((const char*)Bs + bbase + nj * 2048 + col1);
#pragma unroll
    for (int mi = 0; mi < 4; ++mi)
#pragma unroll
      for (int nj = 0; nj < 4; ++nj)
        acc[mi][nj] = __builtin_amdgcn_mfma_f32_16x16x32_bf16(
            af[mi], bfr[nj], acc[mi][nj], 0, 0, 0);
    __syncthreads();
  }

#pragma unroll
  for (int mi = 0; mi < 4; ++mi) {
#pragma unroll
    for (int nj = 0; nj < 4; ++nj) {
      int col = n0 + wc * 64 + nj * 16 + lr;
      float bv = bias[col];
#pragma unroll
      for (int j = 0; j < 4; ++j) {
        int rowm = m0 + wr * 64 + mi * 16 + lg * 4 + j;
        Out[(size_t)rowm * CC + col] = acc[mi][nj][j] + bv;
      }
    }
  }
}

// ---------------- flash attention v9 + 3-blocks/CU occupancy hint ----------
__global__ __launch_bounds__(256, 3) void attn_fwd9(
    const unsigned short* __restrict__ Q, const unsigned short* __restrict__ K,
    const unsigned short* __restrict__ Vt, const float* __restrict__ m01,
    unsigned short* __restrict__ O) {
  __shared__ __attribute__((aligned(64))) char ldsb[40960];
  const int t = threadIdx.x, l = t & 63, w = t >> 6;
  const int q5 = l & 31, hig = l >> 5;
  const bool hib = hig != 0;
  int lin = blockIdx.y * gridDim.x + blockIdx.x;
  int sw = (lin & 7) * 128 + (lin >> 3);
  const int bx = sw & 15, bh = sw >> 4;
  const int b_ = bh >> 4, h_ = bh & (NH - 1);
  const int q = bx * 128 + w * 32 + q5;
  const size_t base = (size_t)bh * TT * HD;
  const unsigned short* Kg = K + base;
  const unsigned short* Vg = Vt + (size_t)bh * HD * TT;

  bf16x8 qf[4];
  {
    const unsigned short* qp = Q + base + (size_t)q * HD + 8 * hig;
#pragma unroll
    for (int dk = 0; dk < 4; ++dk) qf[dk] = *(const bf16x8*)(qp + dk * 16);
  }

  int ka[4];
  {
    int swz = (q5 & 7) << 4;
#pragma unroll
    for (int dk = 0; dk < 4; ++dk)
      ka[dk] = q5 * 128 + ((dk * 32 + hig * 16) ^ swz);
  }
  int moff = 32768 + hig * 16;

  const int s1 = t + 256;
  const int r0 = t >> 3, c0 = (t & 7) * 16, x0 = c0 ^ ((r0 & 7) << 4);
  const int r1 = s1 >> 3, c1 = (s1 & 7) * 16, x1 = c1 ^ ((r1 & 7) << 4);
  const unsigned short* gk0 = Kg + r0 * HD + (x0 >> 1);
  const unsigned short* gk1 = Kg + r1 * HD + (x1 >> 1);
  const unsigned short* gv0 = Vg + (size_t)r0 * TT + (x0 >> 1);
  const unsigned short* gv1 = Vg + (size_t)r1 * TT + (x1 >> 1);

  auto stage = [&](int boff) {
    g2l16(gk0, ldsb + t * 16 + boff);
    g2l16(gk1, ldsb + t * 16 + 4096 + boff);
    g2l16(gv0, ldsb + 16384 + t * 16 + boff);
    g2l16(gv1, ldsb + 16384 + t * 16 + 4096 + boff);
    gk0 += 4096; gk1 += 4096; gv0 += 64; gv1 += 64;
  };

  f32x16 ot[2];
#pragma unroll
  for (int i = 0; i < 16; ++i) { ot[0][i] = 0.f; ot[1][i] = 0.f; }
  float l0 = 0.f, l1 = 0.f, l2 = 0.f, l3 = 0.f;

  {
    const float* mg = m01 + (size_t)b_ * TT;
#pragma unroll
    for (int i = 0; i < 2; ++i) {
      int s = t + i * 256;
      g2l16(mg + s * 4, ldsb + 32768 + s * 16);
    }
  }
  stage(0);
  asm volatile("s_waitcnt vmcnt(0)" ::: "memory");
  __syncthreads();

  auto compute = [&](auto Bc) {
    constexpr int BO = decltype(Bc)::value;
    constexpr int MO = BO ? 256 : 0;
#pragma unroll
    for (int kk = 0; kk < 2; ++kk) {
      f32x16 s = {};
      __builtin_amdgcn_s_setprio(1);
#pragma unroll
      for (int dk = 0; dk < 4; ++dk) {
        bf16x8 kf = *(const bf16x8*)(ldsb + ka[dk] + kk * 4096 + BO);
        s = __builtin_amdgcn_mfma_f32_32x32x16_bf16(kf, qf[dk], s, 0, 0, 0);
      }
      __builtin_amdgcn_s_setprio(0);

      unsigned int wl[4], wh[4];
#pragma unroll
      for (int g = 0; g < 4; ++g) {
        int i = g * 4;
        float e0 = fast_exp2(s[i + 0]);
        float e1 = fast_exp2(s[i + 1]);
        float e2 = fast_exp2(s[i + 2]);
        float e3 = fast_exp2(s[i + 3]);
        f32x4 mk = *(const f32x4*)(ldsb + moff + MO + kk * 128 + g * 32);
        l0 = fmaf(e0, mk[0], l0);
        l1 = fmaf(e1, mk[1], l1);
        l2 = fmaf(e2, mk[2], l2);
        l3 = fmaf(e3, mk[3], l3);
        wl[g] = cvtpk(e0, e1);
        wh[g] = cvtpk(e2, e3);
      }

      bf16x8 pa[2];
#pragma unroll
      for (int kh = 0; kh < 2; ++kh) {
        const int gA = 2 * kh, gB = gA + 1;
        unsigned int a0 = wl[gA], b0 = wl[gB];
        unsigned int a1 = wh[gA], b1 = wh[gB];
        plswap(a0, b0);
        plswap(a1, b1);
        unsigned int pw[4] = {a0, a1, b0, b1};
        pa[kh] = *(bf16x8*)pw;
      }

      __builtin_amdgcn_s_setprio(1);
#pragma unroll
      for (int kh = 0; kh < 2; ++kh) {
        const int ks = kk * 2 + kh;
        bf16x8 vf0 = *(const bf16x8*)(ldsb + ka[ks] + 16384 + BO);
        bf16x8 vf1 = *(const bf16x8*)(ldsb + ka[ks] + 16384 + 4096 + BO);
        ot[0] = __builtin_amdgcn_mfma_f32_32x32x16_bf16(vf0, pa[kh], ot[0], 0, 0, 0);
        ot[1] = __builtin_amdgcn_mfma_f32_32x32x16_bf16(vf1, pa[kh], ot[1], 0, 0, 0);
      }
      __builtin_amdgcn_s_setprio(0);
    }
  };

  for (int j = 0; j < 16; ++j) {
    stage(8192);
    compute(std::integral_constant<int, 0>{});
    asm volatile("s_waitcnt vmcnt(0)" ::: "memory");
    __syncthreads();
    if (j < 15) stage(0);
    compute(std::integral_constant<int, 8192>{});
    asm volatile("s_waitcnt vmcnt(0)" ::: "memory");
    __syncthreads();
    moff += 512;
  }

  float l_ = (l0 + l1) + (l2 + l3);
  float l_tot = l_ + partner32(l_, hib);
  const float inv = 1.f / l_tot;
  unsigned short* orow = O + ((size_t)(b_ * TT) + q) * CC + h_ * 64 + 4 * hig;
#pragma unroll
  for (int dt = 0; dt < 2; ++dt)
#pragma unroll
    for (int g = 0; g < 4; ++g) {
      unsigned short pk4[4];
#pragma unroll
      for (int j = 0; j < 4; ++j) pk4[j] = f2bf(ot[dt][4 * g + j] * inv);
      *(ushort4*)(orow + dt * 32 + 8 * g) = *(ushort4*)pk4;
    }
}

extern "C" void kernel_launch(void* const* d_in, const int* in_sizes, int n_in,
                              void* d_out, int out_size, void* d_ws, size_t ws_size,
                              hipStream_t stream) {
  const float* x  = (const float*)d_in[0];
  const float* ft = (const float*)d_in[1];
  const int* mask = (const int*)d_in[2];
  const float* wq = (const float*)d_in[3];
  const float* bq = (const float*)d_in[4];
  const float* wk = (const float*)d_in[5];
  const float* bk = (const float*)d_in[6];
  const float* wv = (const float*)d_in[7];
  const float* bv = (const float*)d_in[8];
  const float* wo = (const float*)d_in[9];
  const float* bo = (const float*)d_in[10];
  float* out = (float*)d_out;

  char* ws = (char*)d_ws;
  const size_t NTOK = (size_t)BB * TT;   // 8192
  const size_t SB = NTOK * CC * 2;       // 16 MiB
  unsigned short* xb   = (unsigned short*)ws; ws += SB;
  unsigned short* fb   = (unsigned short*)ws; ws += SB;
  unsigned short* Qb   = (unsigned short*)ws; ws += SB;
  unsigned short* Kb   = (unsigned short*)ws; ws += SB;
  unsigned short* Vtb  = (unsigned short*)ws; ws += SB;   // V^T (b,h,d,t)
  unsigned short* AO   = (unsigned short*)ws; ws += SB;
  unsigned short* wqkvt = (unsigned short*)ws; ws += (size_t)3 * CC * CC * 2;
  unsigned short* wot   = (unsigned short*)ws; ws += (size_t)CC * CC * 2;
  float* m01 = (float*)ws; ws += NTOK * 4;

  prep_fused<<<20512, 256, 0, stream>>>(x, ft, wq, wk, wv, wo, mask,
                                        xb, fb, wqkvt, wot, m01);

  const float qscale = 0.125f * 1.44269504f;  // 1/sqrt(64) * log2(e)
  dim3 gq(24, 64);  // 1536 blocks
  gemm_qkv<<<gq, 256, 0, stream>>>(xb, fb, wqkvt, bq, bk, bv, m01,
                                   Qb, Kb, Vtb, qscale);

  dim3 ga(16, 64);  // 1024 blocks
  attn_fwd9<<<ga, 256, 0, stream>>>(Qb, Kb, Vtb, m01, AO);

  dim3 go(8, 64);   // 512 blocks
  gemm_out<<<go, 256, 0, stream>>>(AO, wot, bo, out);
}